// Round 3
// baseline (333.507 us; speedup 1.0000x reference)
//
#include <hip/hip_runtime.h>

// Problem constants
#define B_     16384
#define TD     512     // T*D
#define HID    128
#define LAT    512     // N_TOKENS*CODE_DIM
#define NCODES 512
#define CDIM   64
#define NTOK   8
#define EPS    1e-5f
#define MARGIN 0.02f   // ~10x worst-case approx-distance error (2.6e-3) post-LN

typedef unsigned short u16;
typedef unsigned int   u32;
typedef short bf16x8 __attribute__((ext_vector_type(8)));   // 8 bf16 = 4 VGPR (MFMA A/B frag)
typedef float f32x4  __attribute__((ext_vector_type(4)));   // MFMA C/D frag

__device__ __forceinline__ u16 bf16_rn(float f){
    u32 u = __float_as_uint(f);
    return (u16)((u + 0x7fffu + ((u >> 16) & 1u)) >> 16);   // round-nearest-even
}
__device__ __forceinline__ float bf16_f(u16 h){ return __uint_as_float(((u32)h) << 16); }
__device__ __forceinline__ void split2(float f, u16& hi, u16& lo){
    hi = bf16_rn(f);
    lo = bf16_rn(f - bf16_f(hi));     // residual: |a - hi - lo| <= ~2^-18 |a|
}
#define MFMA16(a,b,c) __builtin_amdgcn_mfma_f32_16x16x32_bf16((a),(b),(c),0,0,0)

// ---------------------------------------------------------------------------
// Prep: c2[c] = ||codebook[c]||^2 (fp32 exact)
// ---------------------------------------------------------------------------
__global__ void c2_kernel(const float* __restrict__ cb, float* __restrict__ c2) {
    int c = blockIdx.x;
    int d = threadIdx.x;            // 64 threads = 1 wave
    float v = cb[c * CDIM + d];
    float s = v * v;
#pragma unroll
    for (int m = 32; m >= 1; m >>= 1) s += __shfl_xor(s, m, 64);
    if (d == 0) c2[c] = s;
}

// ---------------------------------------------------------------------------
// Prep: transpose+split W[K][N] -> hi/lo planes [N][K] (bf16)
// ---------------------------------------------------------------------------
__global__ void tsplit_kernel(const float* __restrict__ W, u16* __restrict__ hi,
                              u16* __restrict__ lo, int N, int kshift){
    int id = blockIdx.x * 256 + threadIdx.x;    // over N*K output elems
    int K = 1 << kshift;
    int n = id >> kshift, k = id & (K - 1);
    u16 h, l2; split2(W[(size_t)k * N + n], h, l2);
    hi[id] = h; lo[id] = l2;
}
// Prep: split codebook [512][64] (no transpose)
__global__ void csplit_kernel(const float* __restrict__ C, u16* __restrict__ hi,
                              u16* __restrict__ lo){
    int id = blockIdx.x * 256 + threadIdx.x;
    u16 h, l2; split2(C[id], h, l2);
    hi[id] = h; lo[id] = l2;
}

// ---------------------------------------------------------------------------
// Prep: P[c][t][j] = sum_k cb[c][k] * dec_w1[t*64+k][j]   (fp32 exact-class)
// Replaces decoder GEMM1: h = relu(b1 + sum_t P[idx_t][t][:]).
// grid (512 codes, 8 slots), 128 threads (j).
// ---------------------------------------------------------------------------
__global__ void pprep_kernel(const float* __restrict__ cb, const float* __restrict__ dw1,
                             float* __restrict__ P){
    int c = blockIdx.x, t = blockIdx.y, j = threadIdx.x;
    const float* wp = dw1 + (size_t)t * 64 * HID + j;
    const float* cp = cb + (size_t)c * CDIM;
    float acc = 0.f;
#pragma unroll
    for (int k = 0; k < 64; ++k) acc = fmaf(cp[k], wp[(size_t)k * HID], acc);
    P[((size_t)c * 8 + t) * HID + j] = acc;
}

// ---------------------------------------------------------------------------
// ENCODER PATH (must match fp32 reference numerics class): baseline VALU fp32
// tiled GEMM. [proven-passing baseline — do not touch]
// ---------------------------------------------------------------------------
template<bool RELU, bool LN>
__launch_bounds__(256)
__global__ void gemm_kernel(const float* __restrict__ A, const float* __restrict__ W,
                            const float* __restrict__ bias,
                            float* __restrict__ C,
                            int M, int N, int K) {
    constexpr int BM = 64, BN = 64, BK = 32;
    __shared__ float As[BK][BM + 4];   // transposed: As[k][m]
    __shared__ float Ws[BK][BN + 4];

    const int tid = threadIdx.x;
    const int tx  = tid & 15;          // 0..15 (cols)
    const int ty  = tid >> 4;          // 0..15 (rows)
    const int m0  = blockIdx.x * BM;
    const int n0  = blockIdx.y * BN;

    float acc[4][4] = {};

    for (int k0 = 0; k0 < K; k0 += BK) {
        {
            int r  = tid >> 3;               // 0..31
            int c4 = (tid & 7) * 4;          // 0..28
#pragma unroll
            for (int h = 0; h < 2; ++h) {
                int rr = r + h * 32;
                float4 v = *(const float4*)&A[(size_t)(m0 + rr) * K + k0 + c4];
                As[c4 + 0][rr] = v.x; As[c4 + 1][rr] = v.y;
                As[c4 + 2][rr] = v.z; As[c4 + 3][rr] = v.w;
            }
        }
        {
            int r  = tid >> 4;               // 0..15
            int c4 = (tid & 15) * 4;         // 0..60
#pragma unroll
            for (int h = 0; h < 2; ++h) {
                int rr = r + h * 16;
                float4 v = *(const float4*)&W[(size_t)(k0 + rr) * N + n0 + c4];
                *(float4*)&Ws[rr][c4] = v;
            }
        }
        __syncthreads();

#pragma unroll
        for (int kk = 0; kk < BK; ++kk) {
            float4 a = *(const float4*)&As[kk][ty * 4];
            float4 b = *(const float4*)&Ws[kk][tx * 4];
            float av[4] = {a.x, a.y, a.z, a.w};
            float bv[4] = {b.x, b.y, b.z, b.w};
#pragma unroll
            for (int i = 0; i < 4; ++i)
#pragma unroll
                for (int j = 0; j < 4; ++j)
                    acc[i][j] = fmaf(av[i], bv[j], acc[i][j]);
        }
        __syncthreads();
    }

    float bv[4];
#pragma unroll
    for (int j = 0; j < 4; ++j) bv[j] = bias[n0 + tx * 4 + j];

#pragma unroll
    for (int i = 0; i < 4; ++i) {
        float c[4];
#pragma unroll
        for (int j = 0; j < 4; ++j) {
            c[j] = acc[i][j] + bv[j];
            if (RELU) c[j] = fmaxf(c[j], 0.0f);
        }
        if (LN) {
            float s  = c[0] + c[1] + c[2] + c[3];
            float ss = c[0]*c[0] + c[1]*c[1] + c[2]*c[2] + c[3]*c[3];
#pragma unroll
            for (int m = 1; m <= 8; m <<= 1) {
                s  += __shfl_xor(s,  m, 64);
                ss += __shfl_xor(ss, m, 64);
            }
            float mean = s * (1.0f / 64.0f);
            float var  = ss * (1.0f / 64.0f) - mean * mean;
            float rstd = rsqrtf(var + EPS);
#pragma unroll
            for (int j = 0; j < 4; ++j) c[j] = (c[j] - mean) * rstd;
        }
        size_t row = (size_t)(m0 + ty * 4 + i);
        *(float4*)&C[row * N + n0 + tx * 4] = make_float4(c[0], c[1], c[2], c[3]);
    }
}

// ---------------------------------------------------------------------------
// DECODER GEMM2: split-bf16 MFMA GEMM (3-pass Markidis), pre-split A planes.
// Block 256 thr = 4 waves (2Mx2N), BM=128, BN=128, BK=32.
// ---------------------------------------------------------------------------
template<int BM, bool AFP32, bool RELU, bool SPLITOUT>
__launch_bounds__(256, 2)
__global__ void gemm_split(const float* __restrict__ Af,
                           const u16* __restrict__ Ahi, const u16* __restrict__ Alo,
                           const u16* __restrict__ Bhi, const u16* __restrict__ Blo,
                           const float* __restrict__ bias,
                           u16* __restrict__ Ohi, u16* __restrict__ Olo,
                           float* __restrict__ Of,
                           int M, int N, int K)
{
    constexpr int WM  = BM / 2;
    constexpr int MI  = WM / 16;
    constexpr int AIT = BM / 32;

    __shared__ uint4 As[2][BM * 4];
    __shared__ uint4 Bs[2][128 * 4];

    const int tid = threadIdx.x;
    const int wid = tid >> 6, l = tid & 63, ln = l & 15, kg = l >> 4;
    const int mw = wid >> 1, nw = wid & 1;
    const int m0 = blockIdx.x * BM, n0 = blockIdx.y * 128;
    const int swz = (ln >> 1) & 3;

    f32x4 acc[MI][4];
#pragma unroll
    for (int i = 0; i < MI; ++i)
#pragma unroll
        for (int j = 0; j < 4; ++j) acc[i][j] = (f32x4){0.f, 0.f, 0.f, 0.f};

    float4 rx0, rx1;
    uint4  ra[AIT > 0 ? AIT : 1];
    uint4  rb[4];

    const int axr = tid >> 2, axc = tid & 3;

    auto gload = [&](int k0){
        if constexpr (AFP32){
            const float* p = Af + (size_t)(m0 + axr) * K + k0 + axc * 8;
            rx0 = *(const float4*)p; rx1 = *(const float4*)(p + 4);
        } else {
#pragma unroll
            for (int h = 0; h < AIT; ++h){
                int idx = tid + 256 * h; int r = idx >> 3, pl = (idx >> 2) & 1, c = idx & 3;
                const u16* p = (pl ? Alo : Ahi) + (size_t)(m0 + r) * K + k0 + c * 8;
                ra[h] = *(const uint4*)p;
            }
        }
#pragma unroll
        for (int h = 0; h < 4; ++h){
            int idx = tid + 256 * h; int r = idx >> 3, pl = (idx >> 2) & 1, c = idx & 3;
            const u16* p = (pl ? Blo : Bhi) + (size_t)(n0 + r) * K + k0 + c * 8;
            rb[h] = *(const uint4*)p;
        }
    };
    auto lstore = [&](){
        if constexpr (AFP32){
            u16 hs[8] __attribute__((aligned(16)));
            u16 ls[8] __attribute__((aligned(16)));
            float v[8] = {rx0.x, rx0.y, rx0.z, rx0.w, rx1.x, rx1.y, rx1.z, rx1.w};
#pragma unroll
            for (int j = 0; j < 8; ++j) split2(v[j], hs[j], ls[j]);
            int pc = axc ^ ((axr >> 1) & 3);
            As[0][axr * 4 + pc] = *(const uint4*)hs;
            As[1][axr * 4 + pc] = *(const uint4*)ls;
        } else {
#pragma unroll
            for (int h = 0; h < AIT; ++h){
                int idx = tid + 256 * h; int r = idx >> 3, pl = (idx >> 2) & 1, c = idx & 3;
                As[pl][r * 4 + (c ^ ((r >> 1) & 3))] = ra[h];
            }
        }
#pragma unroll
        for (int h = 0; h < 4; ++h){
            int idx = tid + 256 * h; int r = idx >> 3, pl = (idx >> 2) & 1, c = idx & 3;
            Bs[pl][r * 4 + (c ^ ((r >> 1) & 3))] = rb[h];
        }
    };

    gload(0);
    for (int k0 = 0; k0 < K; k0 += 32){
        if (k0) __syncthreads();
        lstore();
        __syncthreads();
        if (k0 + 32 < K) gload(k0 + 32);

        bf16x8 af[MI][2], bfr[4][2];
#pragma unroll
        for (int mi = 0; mi < MI; ++mi){
            int r = mw * WM + mi * 16 + ln;
            af[mi][0] = *(bf16x8*)&As[0][r * 4 + (kg ^ swz)];
            af[mi][1] = *(bf16x8*)&As[1][r * 4 + (kg ^ swz)];
        }
#pragma unroll
        for (int ni = 0; ni < 4; ++ni){
            int r = nw * 64 + ni * 16 + ln;
            bfr[ni][0] = *(bf16x8*)&Bs[0][r * 4 + (kg ^ swz)];
            bfr[ni][1] = *(bf16x8*)&Bs[1][r * 4 + (kg ^ swz)];
        }
#pragma unroll
        for (int mi = 0; mi < MI; ++mi)
#pragma unroll
            for (int ni = 0; ni < 4; ++ni){
                acc[mi][ni] = MFMA16(af[mi][0], bfr[ni][0], acc[mi][ni]);  // hi*hi
                acc[mi][ni] = MFMA16(af[mi][0], bfr[ni][1], acc[mi][ni]);  // hi*lo
                acc[mi][ni] = MFMA16(af[mi][1], bfr[ni][0], acc[mi][ni]);  // lo*hi
            }
    }

    float bv[4];
#pragma unroll
    for (int ni = 0; ni < 4; ++ni) bv[ni] = bias[n0 + nw * 64 + ni * 16 + ln];

#pragma unroll
    for (int mi = 0; mi < MI; ++mi){
#pragma unroll
        for (int r = 0; r < 4; ++r){
            float v[4];
#pragma unroll
            for (int ni = 0; ni < 4; ++ni){
                v[ni] = acc[mi][ni][r] + bv[ni];
                if constexpr (RELU) v[ni] = fmaxf(v[ni], 0.f);
            }
            size_t row = (size_t)(m0 + mw * WM + mi * 16 + kg * 4 + r);
#pragma unroll
            for (int ni = 0; ni < 4; ++ni){
                int col = n0 + nw * 64 + ni * 16 + ln;
                if constexpr (SPLITOUT){
                    u16 h, lo2; split2(v[ni], h, lo2);
                    Ohi[row * N + col] = h;  Olo[row * N + col] = lo2;
                } else {
                    Of[row * N + col] = v[ni];
                }
            }
        }
    }
}

// ---------------------------------------------------------------------------
// VQ fused: block = 64 tokens (= 8 samples), 4 waves; wave w owns tokens
// w*16..w*16+15 and scores ALL codes for them (no cross-wave combine).
// z read once from global fp32, split in-reg to A-frags. Codebook in 64-code
// LDS chunks, double-buffered, reg-staged prefetch. dist = c2[c] - 2*cross.
// Exact-fp32 margin rescue. Tail: zq/idx outputs + fused dec-GEMM1 via
// P-table gather (h planes written pre-split for dec GEMM2).
// ---------------------------------------------------------------------------
__launch_bounds__(256, 4)
__global__ void vq_fused(const float* __restrict__ zln,
                         const u16* __restrict__ Chi, const u16* __restrict__ Clo,
                         const float* __restrict__ cbf, const float* __restrict__ c2,
                         const float* __restrict__ Ptab, const float* __restrict__ db1,
                         float* __restrict__ zq_o, float* __restrict__ idx_o,
                         u16* __restrict__ h_h, u16* __restrict__ h_l)
{
    __shared__ uint4 Bz[2][2][64][8];   // [buf][plane][code][16B slot], slot^=(code&7)
    __shared__ float c2s[NCODES];
    __shared__ int   fI[64];
    __shared__ float zf[64];
    __shared__ int   nflag;
    __shared__ int   flagR[64];
    __shared__ float wB[4];
    __shared__ int   wI[4];

    const int tid = threadIdx.x;
    const int wid = tid >> 6, l = tid & 63, ln = l & 15, kg = l >> 4;
    const int m0  = blockIdx.x * 64;

    uint4 rb[4];
    auto gload = [&](int c0){
#pragma unroll
        for (int h = 0; h < 4; ++h){
            int idx = tid + 256 * h;            // 0..1023
            int pl = idx >> 9, r = (idx >> 3) & 63, c = idx & 7;
            const u16* p = (pl ? Clo : Chi) + (size_t)(c0 + r) * CDIM + c * 8;
            rb[h] = *(const uint4*)p;
        }
    };
    auto lstore = [&](int buf){
#pragma unroll
        for (int h = 0; h < 4; ++h){
            int idx = tid + 256 * h;
            int pl = idx >> 9, r = (idx >> 3) & 63, c = idx & 7;
            Bz[buf][pl][r][c ^ (r & 7)] = rb[h];
        }
    };

    gload(0);
    c2s[tid] = c2[tid]; c2s[tid + 256] = c2[tid + 256];
    if (tid == 0) nflag = 0;

    // A-frags: this wave's 16 tokens, straight from global fp32 z, split in-reg
    bf16x8 a[2][2];   // [ks][plane]
    {
        int tok = m0 + wid * 16 + ln;
        const float* zp = zln + (size_t)tok * CDIM + kg * 8;
#pragma unroll
        for (int ks = 0; ks < 2; ++ks){
            float4 v0 = *(const float4*)(zp + ks * 32);
            float4 v1 = *(const float4*)(zp + ks * 32 + 4);
            u16 hs[8] __attribute__((aligned(16)));
            u16 ls[8] __attribute__((aligned(16)));
            float vv[8] = {v0.x, v0.y, v0.z, v0.w, v1.x, v1.y, v1.z, v1.w};
#pragma unroll
            for (int j2 = 0; j2 < 8; ++j2) split2(vv[j2], hs[j2], ls[j2]);
            a[ks][0] = *(const bf16x8*)hs;
            a[ks][1] = *(const bf16x8*)ls;
        }
    }

    lstore(0);
    __syncthreads();

    float b1[4], b2[4]; int i1[4];
#pragma unroll
    for (int r = 0; r < 4; ++r){ b1[r] = 3.4e38f; b2[r] = 3.4e38f; i1[r] = 0; }

    for (int cc = 0; cc < 8; ++cc){
        const int buf = cc & 1;
        if (cc < 7) gload((cc + 1) * 64);

        f32x4 acc[4];
#pragma unroll
        for (int ni = 0; ni < 4; ++ni){
            int r = ni * 16 + ln, sw = r & 7;
            const uint4* Bh = &Bz[buf][0][r][0];
            const uint4* Bl = &Bz[buf][1][r][0];
            bf16x8 b0h = *(const bf16x8*)&Bh[kg ^ sw];
            bf16x8 b1h = *(const bf16x8*)&Bh[(4 + kg) ^ sw];
            bf16x8 b0l = *(const bf16x8*)&Bl[kg ^ sw];
            bf16x8 b1l = *(const bf16x8*)&Bl[(4 + kg) ^ sw];
            f32x4 t4 = (f32x4){0.f, 0.f, 0.f, 0.f};
            t4 = MFMA16(a[0][0], b0h, t4);   // hiA*hiB  ks0
            t4 = MFMA16(a[0][0], b0l, t4);   // hiA*loB  ks0
            t4 = MFMA16(a[0][1], b0h, t4);   // loA*hiB  ks0
            t4 = MFMA16(a[1][0], b1h, t4);   // ks1
            t4 = MFMA16(a[1][0], b1l, t4);
            t4 = MFMA16(a[1][1], b1h, t4);
            acc[ni] = t4;
        }
        // score: per lane, codes ascend with (cc, ni) -> strict < keeps lowest idx
#pragma unroll
        for (int ni = 0; ni < 4; ++ni){
            int code = cc * 64 + ni * 16 + ln;
            float cv = c2s[code];
#pragma unroll
            for (int r = 0; r < 4; ++r){
                float d = fmaf(-2.f, acc[ni][r], cv);
                if (d < b1[r]) { b2[r] = b1[r]; b1[r] = d; i1[r] = code; }
                else if (d < b2[r]) b2[r] = d;
            }
        }
        if (cc < 7){
            __syncthreads();     // all waves done reading buf^1 (their prev iter)
            lstore(buf ^ 1);
            __syncthreads();     // writes visible before next iter reads
        }
    }

    // 16-lane butterfly per token (tie-break to lower idx); 2nd-best for margin
#pragma unroll
    for (int r = 0; r < 4; ++r){
        float v1 = b1[r], v2 = b2[r]; int ii = i1[r];
#pragma unroll
        for (int mk = 1; mk <= 8; mk <<= 1){
            float o1 = __shfl_xor(v1, mk, 64), o2 = __shfl_xor(v2, mk, 64);
            int   oi = __shfl_xor(ii, mk, 64);
            float n2 = fminf(fmaxf(v1, o1), fminf(v2, o2));
            if (o1 < v1 || (o1 == v1 && oi < ii)){ v1 = o1; ii = oi; }
            v2 = n2;
        }
        if (ln == 0){
            int row = wid * 16 + kg * 4 + r;
            fI[row] = ii;
            if (v2 - v1 < MARGIN){ int s2 = atomicAdd(&nflag, 1); flagR[s2] = row; }
        }
    }
    __syncthreads();

    // exact fp32 rescue for ambiguous tokens (reads true fp32 z)
    int nf = nflag;
    for (int f = 0; f < nf; ++f){
        int row = flagR[f];
        if (tid < 64) zf[tid] = zln[(size_t)(m0 + row) * CDIM + tid];
        __syncthreads();
        float bb = 3.4e38f; int bi = 0;
#pragma unroll
        for (int cH = 0; cH < 2; ++cH){
            int ccode = tid + 256 * cH;
            const float* cp = cbf + (size_t)ccode * CDIM;
            float dot = 0.f;
#pragma unroll
            for (int dd = 0; dd < 64; ++dd) dot = fmaf(zf[dd], cp[dd], dot);
            float d = fmaf(-2.f, dot, c2s[ccode]);
            if (d < bb){ bb = d; bi = ccode; }
        }
#pragma unroll
        for (int mk = 1; mk < 64; mk <<= 1){
            float o = __shfl_xor(bb, mk, 64); int oi = __shfl_xor(bi, mk, 64);
            if (o < bb || (o == bb && oi < bi)){ bb = o; bi = oi; }
        }
        if (l == 0){ wB[wid] = bb; wI[wid] = bi; }
        __syncthreads();
        if (tid == 0){
            float v1 = wB[0]; int ii = wI[0];
#pragma unroll
            for (int w2 = 1; w2 < 4; ++w2)
                if (wB[w2] < v1 || (wB[w2] == v1 && wI[w2] < ii)){ v1 = wB[w2]; ii = wI[w2]; }
            fI[row] = ii;
        }
        __syncthreads();
    }

    // outputs: zq (fp32 exact gather) + indices
    {
        int row = tid >> 2, part = tid & 3;
        int ii  = fI[row];
        size_t gr = (size_t)(m0 + row);
        const float* cf = cbf + (size_t)ii * CDIM + part * 16;
        float4 q0 = *(const float4*)(cf + 0),  q1 = *(const float4*)(cf + 4);
        float4 q2 = *(const float4*)(cf + 8),  q3 = *(const float4*)(cf + 12);
        float* zo = zq_o + gr * CDIM + part * 16;
        *(float4*)(zo + 0) = q0; *(float4*)(zo + 4)  = q1;
        *(float4*)(zo + 8) = q2; *(float4*)(zo + 12) = q3;
        if (part == 0) idx_o[gr] = (float)ii;
    }

    // fused decoder GEMM1 via P-table: h = relu(b1 + sum_t P[idx_t][t][:])
    // block = samples blockIdx.x*8 .. +7; 32 threads per sample, 4 cols each
    {
        int s  = tid >> 5;                 // 0..7
        int j0 = (tid & 31) * 4;           // 0..124
        float4 hv = *(const float4*)&db1[j0];
#pragma unroll
        for (int t = 0; t < 8; ++t){
            int c = fI[s * 8 + t];
            const float* pp = Ptab + ((size_t)c * 8 + t) * HID + j0;
            float4 p = *(const float4*)pp;
            hv.x += p.x; hv.y += p.y; hv.z += p.z; hv.w += p.w;
        }
        hv.x = fmaxf(hv.x, 0.f); hv.y = fmaxf(hv.y, 0.f);
        hv.z = fmaxf(hv.z, 0.f); hv.w = fmaxf(hv.w, 0.f);
        u16 hh[4] __attribute__((aligned(8)));
        u16 ll[4] __attribute__((aligned(8)));
        split2(hv.x, hh[0], ll[0]); split2(hv.y, hh[1], ll[1]);
        split2(hv.z, hh[2], ll[2]); split2(hv.w, hh[3], ll[3]);
        size_t hrow = ((size_t)blockIdx.x * 8 + s) * HID + j0;
        *(uint2*)&h_h[hrow] = *(const uint2*)hh;
        *(uint2*)&h_l[hrow] = *(const uint2*)ll;
    }
}

// ---------------------------------------------------------------------------
extern "C" void kernel_launch(void* const* d_in, const int* in_sizes, int n_in,
                              void* d_out, int out_size, void* d_ws, size_t ws_size,
                              hipStream_t stream) {
    const float* x      = (const float*)d_in[0];
    const float* enc_w1 = (const float*)d_in[1];
    const float* enc_b1 = (const float*)d_in[2];
    const float* enc_w2 = (const float*)d_in[3];
    const float* enc_b2 = (const float*)d_in[4];
    const float* cbk    = (const float*)d_in[5];
    const float* dec_w1 = (const float*)d_in[6];
    const float* dec_b1 = (const float*)d_in[7];
    const float* dec_w2 = (const float*)d_in[8];
    const float* dec_b2 = (const float*)d_in[9];

    // outputs, all float32, concatenated flat: recon | z_q | indices
    float* out     = (float*)d_out;
    float* recon_o = out;
    float* zq_o    = out + (size_t)B_ * TD;
    float* idx_o   = out + 2 * (size_t)B_ * TD;

    // workspace carve-up
    float* zbuf  = (float*)d_ws;                       // [B,512] fp32 z (post-LN)
    float* hbuf  = zbuf + (size_t)B_ * TD;             // [B,128] fp32 enc hidden / dec h planes
    float* c2buf = hbuf + (size_t)B_ * HID;            // 512 fp32
    float* Ptab  = c2buf + 512;                        // 512*8*128 fp32 = 2 MB
    u16* w = (u16*)(Ptab + (size_t)NCODES * NTOK * HID);
    u16* d2t_h = w; w += 65536;   u16* d2t_l = w; w += 65536;   // dec_w2^T [512][128]
    u16* cb_h  = w; w += 32768;   u16* cb_l  = w; w += 32768;   // codebook [512][64]
    // decoder hidden planes alias hbuf (hbuf dead after encoder GEMM2)
    u16* h_h = (u16*)hbuf;
    u16* h_l = h_h + (size_t)B_ * HID;

    // ---- prep ----
    hipLaunchKernelGGL(tsplit_kernel, dim3(256), dim3(256), 0, stream, dec_w2, d2t_h, d2t_l, TD, 7);
    hipLaunchKernelGGL(csplit_kernel, dim3(128), dim3(256), 0, stream, cbk, cb_h, cb_l);
    hipLaunchKernelGGL(c2_kernel, dim3(NCODES), dim3(64), 0, stream, cbk, c2buf);
    hipLaunchKernelGGL(pprep_kernel, dim3(NCODES, NTOK), dim3(HID), 0, stream, cbk, dec_w1, Ptab);

    // ---- encoder GEMM1 + ReLU (fp32 VALU): x[16384,512] @ w1 -> hbuf ----
    hipLaunchKernelGGL((gemm_kernel<true, false>), dim3(B_ / 64, HID / 64), dim3(256), 0,
                       stream, x, enc_w1, enc_b1, hbuf, B_, HID, TD);

    // ---- encoder GEMM2 + LN (fp32 VALU): hbuf @ w2 -> zbuf ----
    hipLaunchKernelGGL((gemm_kernel<false, true>), dim3(B_ / 64, LAT / 64), dim3(256), 0,
                       stream, hbuf, enc_w2, enc_b2, zbuf, B_, LAT, HID);

    // ---- VQ fused (MFMA argmin + rescue + zq/idx + P-gather h planes) ----
    hipLaunchKernelGGL(vq_fused, dim3(B_ * NTOK / 64), dim3(256), 0, stream,
                       zbuf, cb_h, cb_l, cbk, c2buf, Ptab, dec_b1,
                       zq_o, idx_o, h_h, h_l);

    // ---- decoder GEMM2 (MFMA): h planes @ dw2 -> recon fp32 ----
    hipLaunchKernelGGL((gemm_split<128, false, false, false>), dim3(B_ / 128, TD / 128), dim3(256), 0,
                       stream, (const float*)nullptr, h_h, h_l,
                       d2t_h, d2t_l, dec_b2, (u16*)nullptr, (u16*)nullptr, recon_o, B_, TD, HID);
}